// Round 7
// baseline (364.967 us; speedup 1.0000x reference)
//
#include <hip/hip_runtime.h>
#include <stdint.h>

// LocalCorrelation on MI355X (gfx950).  R13 = R12 with the barrier discipline
// rebuilt.  R12 post-mortem: ~75% of cycles were waits; cause is the
// documented hipcc behavior of emitting `s_waitcnt vmcnt(0) lgkmcnt(0)`
// before every s_barrier -- our staging loads were issued right before
// __syncthreads, so EVERY kg-step drained the whole 32-load burst inside the
// barrier in lockstep (memory pipe idle during compute, compute idle during
// loads).  Register-staged loads are wave-private: they do NOT need draining
// at a barrier -- only the ds_write pack needs lgkmcnt(0).
// R13: raw `s_waitcnt lgkmcnt(0)` + s_barrier (NO vmcnt drain); staging loads
// stay in flight across the barrier and are consumed with counted vmcnt
// (24/16/8/0) so the fp16 pack pipelines with load arrivals; each counted
// wait followed by sched_barrier(0) (rule #18).  Loads issue at phase top ->
// covered by frag+MFMA.  launch_bounds (512,2): LDS caps at 2 blocks/CU
// anyway; vv[32] must stay live (~130 VGPR).  Everything else = R12.

typedef _Float16 half8 __attribute__((ext_vector_type(8)));
typedef float floatx4 __attribute__((ext_vector_type(4)));

#define B_ 4
#define C_ 256
#define H_ 128
#define W_ 128
#define K2_ 169
#define INV_T 14.285714285714286f
#define HW_ (H_ * W_)  // 16384

// LDS layout per 32 KB buffer (halfs), unchanged from R5/R12:
//   b-px (row,col): (row*28+col)*32 + c   [row 0..15, col 0..27]
//   a-px (r,m):     14336 + (r*16+m)*32 + c
// Frag reads: A[r] at 14336 + (r*16+ml)*32 + q*8 ; B at jj*896 + col*32 + q*8.
union SmemU { _Float16 stage[2][16384]; float ostage[K2_ * 2 * 17]; };  // 64 KB

// pack one 8-channel chunk qq after waiting for its loads (counted vmcnt)
#define PACK_CHUNK(WB, QQ, NW)                                                  \
  do {                                                                          \
    asm volatile("s_waitcnt vmcnt(" #NW ")" ::: "memory");                      \
    __builtin_amdgcn_sched_barrier(0);                                          \
    half8 hh;                                                                   \
    _Pragma("unroll") for (int j = 0; j < 8; ++j) {                             \
      const float x = ok ? vv[(QQ) * 8 + j] : 0.f;                              \
      ss += x * x;                                                              \
      hh[j] = (_Float16)x;                                                      \
    }                                                                           \
    *(half8*)((WB) + (QQ) * 8) = hh;                                            \
  } while (0)

__global__ __launch_bounds__(512, 2) void corr_fused(const float* __restrict__ fa,
                                                     const float* __restrict__ fb,
                                                     float* __restrict__ out) {
  __shared__ SmemU u;
  __shared__ float inv_b[448];
  __shared__ float inv_a[64];
  const int bid = blockIdx.x;
  const int xcd = bid & 7, l = bid >> 3;  // XCD-contiguous h-bands (halo L2 reuse)
  const int bb = l >> 5, hseg = (l >> 3) & 3, wt = l & 7;
  const int hg = xcd * 4 + hseg;
  const int h0 = hg * 4, w0 = wt * 16;
  const int t = threadIdx.x;
  const int lane = t & 63, wv = t >> 6;  // 8 waves
  const int ml = lane & 15, q = lane >> 4;
  const int ntile = wv & 1, jjg = wv >> 1;

  // ---- staging assignment: one thread per pixel, 32 c's per kg ----
  bool ok;
  const float* gp;
  int pxo;  // half offset of this px's row within a stage buffer
  if (t < 448) {  // b-halo: 16 rows x 28 cols
    const int row = t / 28, col = t - row * 28;
    const int rim = h0 - 6 + row, cim = w0 - 6 + col;
    ok = ((unsigned)rim < (unsigned)H_) && ((unsigned)cim < (unsigned)W_);
    gp = fb + (size_t)bb * C_ * HW_ + (ok ? (rim * W_ + cim) : 0);
    pxo = t * 32;
  } else {        // a-tile: 4 rows x 16 cols
    const int px = t - 448;
    const int r = px >> 4, m = px & 15;
    ok = true;
    gp = fa + (size_t)bb * C_ * HW_ + (h0 + r) * W_ + (w0 + m);
    pxo = 14336 + px * 32;
  }

  float ss = 0.f;   // f32 sumsq over all 256 c (raw values, full precision)
  float vv[32];     // staged fp32 for one kg; asm-defined, statically indexed

  // ---- prologue: issue L(0), pack into buf0 with counted vmcnt ----
  #pragma unroll
  for (int cc = 0; cc < 32; ++cc)
    asm volatile("global_load_dword %0, %1, off" : "=v"(vv[cc]) : "v"(gp + (size_t)cc * HW_));
  gp += (size_t)32 * HW_;
  {
    _Float16* wb = u.stage[0] + pxo;
    PACK_CHUNK(wb, 0, 24);
    PACK_CHUNK(wb, 1, 16);
    PACK_CHUNK(wb, 2, 8);
    PACK_CHUNK(wb, 3, 0);
  }
  asm volatile("s_waitcnt lgkmcnt(0)" ::: "memory");
  __builtin_amdgcn_sched_barrier(0);
  __builtin_amdgcn_s_barrier();
  __builtin_amdgcn_sched_barrier(0);

  floatx4 acc[4][4] = {};  // [uu: jj=jjg+4uu][r]; 13 of 16 valid per wave

  #pragma unroll
  for (int kg = 0; kg < 8; ++kg) {
    // issue L(kg+1) at phase top: memory pipe busy under frag+MFMA
    if (kg < 7) {
      #pragma unroll
      for (int cc = 0; cc < 32; ++cc)
        asm volatile("global_load_dword %0, %1, off" : "=v"(vv[cc]) : "v"(gp + (size_t)cc * HW_));
      gp += (size_t)32 * HW_;
    }

    const _Float16* sb = u.stage[kg & 1];
    half8 A[4];
    #pragma unroll
    for (int r = 0; r < 4; ++r)
      A[r] = *(const half8*)(sb + 14336 + (r * 16 + ml) * 32 + q * 8);

    #pragma unroll
    for (int uu = 0; uu < 4; ++uu) {
      const int jj = jjg + 4 * uu;
      const half8 Bf = *(const half8*)(sb + jj * 896 + (ntile * 16 + ml) * 32 + q * 8);
      #pragma unroll
      for (int r = 0; r < 4; ++r) {
        if ((uu == 0 && r > jjg) || (uu == 3 && r < jjg)) continue;  // dy out of band
        acc[uu][r] = __builtin_amdgcn_mfma_f32_16x16x32_f16(A[r], Bf, acc[uu][r], 0, 0, 0);
      }
    }

    // pack L(kg+1) into the other buffer, pipelined with load arrivals;
    // then lgkm-only barrier (loads may NOT be in flight here: last chunk
    // waited vmcnt(0), exact since no other vmem in the loop).
    if (kg < 7) {
      _Float16* wb = u.stage[(kg + 1) & 1] + pxo;
      PACK_CHUNK(wb, 0, 24);
      PACK_CHUNK(wb, 1, 16);
      PACK_CHUNK(wb, 2, 8);
      PACK_CHUNK(wb, 3, 0);
      asm volatile("s_waitcnt lgkmcnt(0)" ::: "memory");
      __builtin_amdgcn_sched_barrier(0);
      __builtin_amdgcn_s_barrier();
      __builtin_amdgcn_sched_barrier(0);
    }
  }

  // ---- inverse norms (f32; OOB px: ss=0 -> dot=0 -> 0) ----
  if (t < 448) inv_b[t] = 1.0f / fmaxf(sqrtf(ss), 1e-12f);
  else         inv_a[t - 448] = INV_T / fmaxf(sqrtf(ss), 1e-12f);
  __syncthreads();  // full drain fine here (nothing outstanding); fences buf0 for ostage

  // ---- epilogue: scale by inv-norms; 2 rounds of 2 rows; ostage overlays buf0 ----
  #pragma unroll
  for (int r2 = 0; r2 < 2; ++r2) {
    if (r2) __syncthreads();
    #pragma unroll
    for (int uu = 0; uu < 4; ++uu) {
      const int jj = jjg + 4 * uu;
      const int col = ntile * 16 + ml;
      const float sbv = (col < 28) ? inv_b[jj * 28 + col] : 0.f;  // col>=28 never stored
      #pragma unroll
      for (int rr = 2 * r2; rr < 2 * r2 + 2; ++rr) {
        if ((uu == 0 && rr > jjg) || (uu == 3 && rr < jjg)) continue;
        const int dy6 = jj - rr;  // in [0,12]
        #pragma unroll
        for (int p = 0; p < 4; ++p) {
          const int ip = q * 4 + p;
          const int dx6 = col - ip;
          if (dx6 >= 0 && dx6 <= 12)
            u.ostage[((dy6 * 13 + dx6) * 2 + (rr & 1)) * 17 + ip] =
                acc[uu][rr][p] * sbv * inv_a[rr * 16 + ip];
        }
      }
    }
    __syncthreads();
    for (int s = t; s < K2_ * 32; s += 512) {
      const int k = s >> 5, r1 = (s >> 4) & 1, ip = s & 15;
      out[(((size_t)bb * K2_ + k) * H_ + h0 + 2 * r2 + r1) * W_ + w0 + ip] =
          u.ostage[(k * 2 + r1) * 17 + ip];
    }
  }
}

extern "C" void kernel_launch(void* const* d_in, const int* in_sizes, int n_in,
                              void* d_out, int out_size, void* d_ws, size_t ws_size,
                              hipStream_t stream) {
  const float* fa = (const float*)d_in[0];
  const float* fb = (const float*)d_in[1];
  float* out = (float*)d_out;
  (void)d_ws; (void)ws_size;  // workspace not needed
  corr_fused<<<1024, 512, 0, stream>>>(fa, fb, out);
}

// Round 8
// 256.171 us; speedup vs baseline: 1.4247x; 1.4247x over previous
//
#include <hip/hip_runtime.h>
#include <stdint.h>

// LocalCorrelation on MI355X (gfx950).  R14 = R12 (verified 105.7 us) + two
// independent fixes.  R13 post-mortem: WRITE_SIZE 254 MB / FETCH 193 MB =
// register-spill scratch traffic (32 asm loads pinned dest+addr VGPRs on top
// of acc[64] -> blew the 128 cap); drain theory never tested.  R14 keeps
// compiler-managed loads.
//  FIX 1 (drain): loads issued AFTER __syncthreads; pack consumes them before
//   the next barrier, so the compiler's pre-barrier vmcnt(0) drain is free
//   (R12 issued loads right before the barrier -> full-latency lockstep stall
//   every phase).
//  FIX 2 (LDS write conflicts, 9.4M cycles in R12): staging ownership
//   (p0=t>>2, sub=t&3), px=p0+128g -> pack write byte = 16*t + 8192g =
//   lane-linear 16B = conflict-free (R12: thread-owns-row -> byte 64t ->
//   32-way).  Sumsq via 4-lane __shfl_xor reduce.  Loads split into two
//   16-reg half-batches packed mid-MFMA: peak live ~124 < 128 (no spill).
// Frag reads / MFMA / epilogue / LDS layout byte-identical to R12.

typedef _Float16 half8 __attribute__((ext_vector_type(8)));
typedef float floatx4 __attribute__((ext_vector_type(4)));

#define B_ 4
#define C_ 256
#define H_ 128
#define W_ 128
#define K2_ 169
#define INV_T 14.285714285714286f
#define HW_ (H_ * W_)  // 16384

// LDS layout per 32 KB buffer (halfs), unchanged from R5/R12:
//   px row p (b: p=row*28+col in [0,448); a: p=448+r*16+m): halfs p*32 + c
// Frag reads: A[r] at 14336 + (r*16+ml)*32 + q*8 ; B at jj*896 + col*32 + q*8.
union SmemU { _Float16 stage[2][16384]; float ostage[K2_ * 2 * 17]; };  // 64 KB

#define LOAD_HALF(HH)                                                          \
  do {                                                                         \
    _Pragma("unroll") for (int g_ = 2 * (HH); g_ < 2 * (HH) + 2; ++g_) {       \
      _Pragma("unroll") for (int j_ = 0; j_ < 8; ++j_)                         \
        vv[(g_ & 1) * 8 + j_] = okg[g_] ? gp[g_][(size_t)j_ * HW_] : 0.f;      \
      gp[g_] += (size_t)32 * HW_;                                              \
    }                                                                          \
  } while (0)

#define PACK_HALF(WB, HH)                                                      \
  do {                                                                         \
    _Pragma("unroll") for (int g_ = 2 * (HH); g_ < 2 * (HH) + 2; ++g_) {       \
      half8 hh_;                                                               \
      _Pragma("unroll") for (int j_ = 0; j_ < 8; ++j_) {                       \
        const float x_ = vv[(g_ & 1) * 8 + j_];                                \
        ssg[g_] += x_ * x_;                                                    \
        hh_[j_] = (_Float16)x_;                                                \
      }                                                                        \
      *(half8*)((WB) + pxo[g_]) = hh_;                                         \
    }                                                                          \
  } while (0)

#define MFMA_UU(UU)                                                            \
  do {                                                                         \
    const int jj_ = jjg + 4 * (UU);                                            \
    const half8 Bf_ =                                                          \
        *(const half8*)(sb + jj_ * 896 + (ntile * 16 + ml) * 32 + q * 8);      \
    _Pragma("unroll") for (int r = 0; r < 4; ++r) {                            \
      if (((UU) == 0 && r > jjg) || ((UU) == 3 && r < jjg)) continue;          \
      acc[(UU)][r] =                                                           \
          __builtin_amdgcn_mfma_f32_16x16x32_f16(A[r], Bf_, acc[(UU)][r], 0, 0, 0); \
    }                                                                          \
  } while (0)

__global__ __launch_bounds__(512, 4) void corr_fused(const float* __restrict__ fa,
                                                     const float* __restrict__ fb,
                                                     float* __restrict__ out) {
  __shared__ SmemU u;
  __shared__ float inv_b[448];
  __shared__ float inv_a[64];
  const int bid = blockIdx.x;
  const int xcd = bid & 7, l = bid >> 3;  // XCD-contiguous h-bands (halo L2 reuse)
  const int bb = l >> 5, hseg = (l >> 3) & 3, wt = l & 7;
  const int hg = xcd * 4 + hseg;
  const int h0 = hg * 4, w0 = wt * 16;
  const int t = threadIdx.x;
  const int lane = t & 63, wv = t >> 6;  // 8 waves
  const int ml = lane & 15, q = lane >> 4;
  const int ntile = wv & 1, jjg = wv >> 1;

  // ---- staging ownership: (px-quad p0, channel-quarter sub); px = p0+128g ----
  const int p0 = t >> 2, sub = t & 3;
  const float* gp[4];
  bool okg[4];
  int pxo[4];  // half offset of this (px, sub) chunk = px*32 + sub*8
  #pragma unroll
  for (int g = 0; g < 4; ++g) {
    const int px = p0 + 128 * g;
    pxo[g] = px * 32 + sub * 8;
    if (px < 448) {  // b-halo: 16 rows x 28 cols
      const int row = px / 28, col = px - row * 28;
      const int rim = h0 - 6 + row, cim = w0 - 6 + col;
      okg[g] = ((unsigned)rim < (unsigned)H_) && ((unsigned)cim < (unsigned)W_);
      gp[g] = fb + (size_t)bb * C_ * HW_ + (size_t)(sub * 8) * HW_ +
              (okg[g] ? (rim * W_ + cim) : 0);
    } else {         // a-tile: 4 rows x 16 cols
      const int ap = px - 448;
      const int r = ap >> 4, m = ap & 15;
      okg[g] = true;
      gp[g] = fa + (size_t)bb * C_ * HW_ + (size_t)(sub * 8) * HW_ +
              (h0 + r) * W_ + (w0 + m);
    }
  }

  float ssg[4] = {0.f, 0.f, 0.f, 0.f};  // per-sub partial sumsq (8 ch x 8 kg)
  float vv[16];                         // half-batch staging regs

  // ---- prologue: load + pack kg0 into buf0 (drained once at first barrier) ----
  LOAD_HALF(0);
  PACK_HALF(u.stage[0], 0);
  LOAD_HALF(1);
  PACK_HALF(u.stage[0], 1);

  floatx4 acc[4][4] = {};  // [uu: jj=jjg+4uu][r]; 13 of 16 valid per wave

  for (int kg = 0; kg < 8; ++kg) {
    __syncthreads();  // fences pack writes to buf[kg&1]; vmcnt already 0 here
    const _Float16* sb = u.stage[kg & 1];
    _Float16* wb = u.stage[(kg + 1) & 1];
    const bool pf = (kg < 7);

    if (pf) LOAD_HALF(0);  // issue AFTER the barrier: consumed before next one

    half8 A[4];
    #pragma unroll
    for (int r = 0; r < 4; ++r)
      A[r] = *(const half8*)(sb + 14336 + (r * 16 + ml) * 32 + q * 8);

    MFMA_UU(0);
    if (pf) { PACK_HALF(wb, 0); LOAD_HALF(1); }
    MFMA_UU(1);
    MFMA_UU(2);
    if (pf) PACK_HALF(wb, 1);
    MFMA_UU(3);
  }

  // ---- sumsq: 4-lane reduce (subs of one px are lanes 4k..4k+3) ----
  #pragma unroll
  for (int g = 0; g < 4; ++g) {
    ssg[g] += __shfl_xor(ssg[g], 1, 64);
    ssg[g] += __shfl_xor(ssg[g], 2, 64);
  }
  if (sub == 0) {
    #pragma unroll
    for (int g = 0; g < 4; ++g) {
      const int px = p0 + 128 * g;
      const float inv = 1.0f / fmaxf(sqrtf(ssg[g]), 1e-12f);
      if (px < 448) inv_b[px] = inv;          // OOB px: staged 0 -> dot 0
      else          inv_a[px - 448] = INV_T * inv;
    }
  }
  __syncthreads();  // fences inv writes; all waves past kg loop (ostage overlays buf0)

  // ---- epilogue: scale by inv-norms; 2 rounds of 2 rows; ostage overlays buf0 ----
  #pragma unroll
  for (int r2 = 0; r2 < 2; ++r2) {
    if (r2) __syncthreads();
    #pragma unroll
    for (int uu = 0; uu < 4; ++uu) {
      const int jj = jjg + 4 * uu;
      const int col = ntile * 16 + ml;
      const float sbv = (col < 28) ? inv_b[jj * 28 + col] : 0.f;  // col>=28 never stored
      #pragma unroll
      for (int rr = 2 * r2; rr < 2 * r2 + 2; ++rr) {
        if ((uu == 0 && rr > jjg) || (uu == 3 && rr < jjg)) continue;
        const int dy6 = jj - rr;  // in [0,12]
        #pragma unroll
        for (int p = 0; p < 4; ++p) {
          const int ip = q * 4 + p;
          const int dx6 = col - ip;
          if (dx6 >= 0 && dx6 <= 12)
            u.ostage[((dy6 * 13 + dx6) * 2 + (rr & 1)) * 17 + ip] =
                acc[uu][rr][p] * sbv * inv_a[rr * 16 + ip];
        }
      }
    }
    __syncthreads();
    for (int s = t; s < K2_ * 32; s += 512) {
      const int k = s >> 5, r1 = (s >> 4) & 1, ip = s & 15;
      out[(((size_t)bb * K2_ + k) * H_ + h0 + 2 * r2 + r1) * W_ + w0 + ip] =
          u.ostage[(k * 2 + r1) * 17 + ip];
    }
  }
}

extern "C" void kernel_launch(void* const* d_in, const int* in_sizes, int n_in,
                              void* d_out, int out_size, void* d_ws, size_t ws_size,
                              hipStream_t stream) {
  const float* fa = (const float*)d_in[0];
  const float* fb = (const float*)d_in[1];
  float* out = (float*)d_out;
  (void)d_ws; (void)ws_size;  // workspace not needed
  corr_fused<<<1024, 512, 0, stream>>>(fa, fb, out);
}